// Round 14
// baseline (197.867 us; speedup 1.0000x reference)
//
#include <hip/hip_runtime.h>

#define C_DIM   128
#define O_MAX   10
#define BN_EPS  1e-5f
#define SLOPE   0.2f

typedef short s8v  __attribute__((ext_vector_type(8)));   // 8 bf16 (4 VGPRs)
typedef float f4v  __attribute__((ext_vector_type(4)));   // MFMA accumulator
#define MFMA(a,b,c) __builtin_amdgcn_mfma_f32_16x16x32_bf16(a,b,c,0,0,0)

__device__ inline unsigned short f2bf(float f) {          // RNE fp32->bf16
    unsigned u = __float_as_uint(f);
    unsigned r = u + 0x7FFFu + ((u >> 16) & 1u);
    return (unsigned short)(r >> 16);
}

// ---------------------------------------------------------------------------
// prep: w1n[n=(kk,oc)][c=128] bf16 ; w2b[oc][k2=tap*64+c] bf16 (tight 576) ;
// zero replicated BN buffers: bn2r[64][64] + bn3r[32][32] = 5120 f.
// ---------------------------------------------------------------------------
#define N_W1N  73728
#define N_W2B  18432       /* 32*576 */
#define N_SUMS 5120        /* 4096 bn2r + 1024 bn3r */
__global__ __launch_bounds__(256) void prep(
    const float* __restrict__ w1, const float* __restrict__ w2,
    short* __restrict__ w1n, short* __restrict__ w2b,
    float* __restrict__ sums)
{
    int i = blockIdx.x * 256 + threadIdx.x;
    if (i < N_W1N) {                       // w1n[n][c] = w1[oc][c][kk], n=kk*64+oc
        int n = i >> 7, c = i & 127;
        int kk = n >> 6, oc = n & 63;
        w1n[i] = f2bf(w1[oc * 1152 + c * 9 + kk]);
        return;
    }
    i -= N_W1N;
    if (i < N_W2B) {                       // w2b[oc][k2], k2 = tap*64+c
        int oc = i / 576, k2 = i % 576;
        int tap = k2 >> 6, c = k2 & 63;
        w2b[i] = f2bf(w2[oc * 576 + c * 9 + tap]);
        return;
    }
    i -= N_W2B;
    if (i < N_SUMS) sums[i] = 0.f;
}

// ---------------------------------------------------------------------------
// stage1 (B/2 = 1024 blocks, 256 thr; TWO images per block).
// __launch_bounds__(256, 6) FORCES VGPR <= ~85 (512/6) — the clean version of
// the r10/r13 WG-rate discriminator (both ran at VGPR 140, occupancy 11%,
// confounding the test).  r12/r13 data: block launch rate 40.5 WG/us at
// VGPR 56 vs 11.4 WG/us at VGPR 140 -> rate degrades with register alloc.
// If rate recovers at VGPR<=85, halved WG count -> stage1 ~25-35 us.
// LDS identical to r12: 25072 B.
// ---------------------------------------------------------------------------
__global__ __launch_bounds__(256, 6) void stage1(
    const float* __restrict__ labels,   // (B,10,128) fp32
    const float* __restrict__ theta,
    const short* __restrict__ w1n,      // (576,128) bf16, n=kk*64+oc
    const short* __restrict__ w2b,      // (32,576) bf16
    const int*   __restrict__ maxobj_p,
    float* __restrict__ h2pre,          // (B,32,4,4)
    float* __restrict__ bn2r)           // (64 reps, 64) s1[0:32] s2[32:64]
{
    __shared__ __align__(16) unsigned char smem[25072];
    short* CPT  = (short*)(smem);             // [p=64][k stride 96]
    short* AT2  = (short*)(smem + 12288);     // [oc=64][k stride 96]
    short* LBF  = (short*)(smem + 12288);     // [m=16][c stride 136] overlay
    short* H1T  = (short*)(smem);             // [pix=100][oc stride 72]
    float* TH   = (float*)(smem + 24576);
    float* CS   = (float*)(smem + 24816);
    float* CS2  = (float*)(smem + 24944);

    const int t = threadIdx.x;
    const int w = t >> 6, l = t & 63, lm = l & 15, lq = l >> 4;
    const int nobj = min(maxobj_p[0], O_MAX);
    const short* brow_base = w1n + (size_t)(w * 144 + lm) * 128 + lq * 8;
    const short* wrow = w2b + (size_t)((w & 1) * 16 + lm) * 576 + lq * 8;

    if (t < 32) CS[t] = 0.f;
    else if (t < 64) CS2[t - 32] = 0.f;

    #pragma unroll 1
    for (int img = 0; img < 2; ++img) {
        const int b = blockIdx.x * 2 + img;

        // ---- phase 0: LBF rows 0-9, rows 10-15 zero; TH; CPT k-tail zero
        for (int i = t; i < 320; i += 256) {             // 10 rows x 32 float4
            float4 v = *(const float4*)&labels[(size_t)b * 1280 + i * 4];
            const int row = i >> 5, c4 = i & 31;
            unsigned lo = f2bf(v.x) | ((unsigned)f2bf(v.y) << 16);
            unsigned hi = f2bf(v.z) | ((unsigned)f2bf(v.w) << 16);
            *(uint2*)&LBF[row * 136 + c4 * 4] = make_uint2(lo, hi);
        }
        for (int i = t; i < 384; i += 256) {             // rows 10-15 x 64 u32
            const int row = 10 + (i >> 6), cu = i & 63;
            *(unsigned*)&LBF[row * 136 + cu * 2] = 0u;
        }
        for (int i = t; i < 384; i += 256) {             // CPT k in [90,96)
            const int p = i / 6, j = i - 6 * p;
            CPT[p * 96 + 90 + j] = 0;
        }
        if (t < 60) TH[t] = theta[b * 60 + t];
        __syncthreads();                                 // (1)

        // ---- afr from LBF, then barrier -> LBF region reusable as AT2
        s8v afr[4];
        #pragma unroll
        for (int ks = 0; ks < 4; ++ks)
            afr[ks] = *(const s8v*)&LBF[lm * 136 + lq * 8 + ks * 32];
        __syncthreads();                                 // (2)

        s8v bcur[4], bnxt[4];
        #pragma unroll
        for (int ks = 0; ks < 4; ++ks)
            bcur[ks] = *(const s8v*)(brow_base + ks * 32);
        #pragma unroll
        for (int ks = 0; ks < 4; ++ks)
            bnxt[ks] = *(const s8v*)(brow_base + 16 * 128 + ks * 32);

        // AT2 k-tail zero (read in conv1, after barrier 3)
        for (int i = t; i < 384; i += 256) {
            const int p = i / 6, j = i - 6 * p;
            AT2[p * 96 + 90 + j] = 0;
        }

        // ---- phase 1a: CPT[p][o*9+kk].  gx,gy affine in (kx,ky).
        for (int i = t; i < 640; i += 256) {             // 64 p x 10 o
            const int p = i & 63, o = i >> 6;
            short* cp = &CPT[p * 96 + o * 9];
            if (o >= nobj) {
                #pragma unroll
                for (int kk = 0; kk < 9; ++kk) cp[kk] = 0;
                continue;
            }
            const int y = p >> 3, x = p & 7;
            const float* tt = &TH[o * 6];
            const float t0 = tt[0], t1 = tt[1], t2 = tt[2];
            const float t3 = tt[3], t4 = tt[4], t5 = tt[5];
            const float X0 = 0.25f * (float)x - 1.0625f;
            const float Y0 = 0.25f * (float)y - 1.0625f;
            const float GX0 = t0 * X0 + t1 * Y0 + t2;
            const float GY0 = t3 * X0 + t4 * Y0 + t5;
            const float dxg = 0.125f * t0, dyg = 0.125f * t1;
            const float dxh = 0.125f * t3, dyh = 0.125f * t4;
            #pragma unroll
            for (int ky = 0; ky < 3; ++ky) {
                const bool oky = (ky == 0) ? (y > 0) : true;  // py<=15 for ky>=1
                const float RX = GX0 + (float)ky * dyg;
                const float RY = GY0 + (float)ky * dyh;
                #pragma unroll
                for (int kx = 0; kx < 3; ++kx) {
                    const bool okx = (kx == 0) ? (x > 0) : true;
                    float val = 0.f;
                    if (oky && okx) {
                        const float gx = RX + (float)kx * dxg;
                        const float gy = RY + (float)kx * dxh;
                        float ix = gx * 8.f + 7.5f;
                        float x0 = floorf(ix), fx = ix - x0;
                        float cx = (1.f - fx) * ((x0 >= 0.f  && x0 <= 15.f) ? 1.f : 0.f)
                                 +        fx  * ((x0 >= -1.f && x0 <= 14.f) ? 1.f : 0.f);
                        float iy = gy * 8.f + 7.5f;
                        float y0 = floorf(iy), fy = iy - y0;
                        float cy = (1.f - fy) * ((y0 >= 0.f  && y0 <= 15.f) ? 1.f : 0.f)
                                 +        fy  * ((y0 >= -1.f && y0 <= 14.f) ? 1.f : 0.f);
                        val = cx * cy;
                    }
                    cp[ky * 3 + kx] = (short)f2bf(val);
                }
            }
        }

        // ---- phase 1b: pipelined A-GEMM. wave w owns n in [w*144,w*144+144)
        #pragma unroll
        for (int nt = 0; nt < 9; ++nt) {
            f4v acc = (f4v){0.f, 0.f, 0.f, 0.f};
            #pragma unroll
            for (int ks = 0; ks < 4; ++ks)
                acc = MFMA(afr[ks], bcur[ks], acc);
            #pragma unroll
            for (int ks = 0; ks < 4; ++ks) bcur[ks] = bnxt[ks];
            if (nt < 7) {
                #pragma unroll
                for (int ks = 0; ks < 4; ++ks)
                    bnxt[ks] = *(const s8v*)(brow_base + (size_t)(nt + 2) * 16 * 128 + ks * 32);
            }
            const int n = w * 144 + nt * 16 + lm;
            const int kk = n >> 6, oc = n & 63;
            #pragma unroll
            for (int r = 0; r < 4; ++r) {
                const int m = lq * 4 + r;
                if (m < 10)
                    AT2[oc * 96 + m * 9 + kk] = (short)f2bf(acc[r]);
            }
        }
        __syncthreads();                                 // (3)

        // ---- conv1 MFMA.  wave w -> oc tile [16w,16w+16); K=96
        f4v c1[4];
        #pragma unroll
        for (int nt = 0; nt < 4; ++nt) c1[nt] = (f4v){0.f, 0.f, 0.f, 0.f};
        {
            const short* at = AT2 + (16 * w + lm) * 96 + lq * 8;
            const short* cp = CPT + lm * 96 + lq * 8;
            #pragma unroll
            for (int ks = 0; ks < 3; ++ks) {
                s8v a = *(const s8v*)(at + ks * 32);
                #pragma unroll
                for (int nt = 0; nt < 4; ++nt) {
                    s8v bb = *(const s8v*)(cp + nt * 1536 + ks * 32);
                    c1[nt] = MFMA(a, bb, c1[nt]);
                }
            }
        }
        __syncthreads();                                 // (4)

        // conv1 epilogue: zero H1T border rows, write lrelu(bf16) interior
        for (int i = t; i < 1152; i += 256) {           // 36 border pix x 32 u32
            const int j = i >> 5, col = i & 31;
            int r;
            if (j < 10) r = j;
            else if (j < 20) r = 90 + (j - 10);
            else { int jj = j - 20; r = 10 + (jj >> 1) * 10 + ((jj & 1) ? 9 : 0); }
            ((unsigned*)H1T)[r * 36 + col] = 0u;
        }
        #pragma unroll
        for (int nt = 0; nt < 4; ++nt) {
            const int p = nt * 16 + lm, y = p >> 3, x = p & 7;
            const int pix = (y + 1) * 10 + (x + 1);
            #pragma unroll
            for (int r = 0; r < 4; ++r) {
                const int oc = 16 * w + lq * 4 + r;
                float v = c1[nt][r];
                v = (v >= 0.f) ? v : SLOPE * v;
                H1T[pix * 72 + oc] = (short)f2bf(v);
            }
        }

        // prefetch conv2 A-operand before barrier
        s8v wa0, wa1;
        if (w < 2) {
            wa0 = *(const s8v*)(wrow);
            wa1 = *(const s8v*)(wrow + 32);
        }
        __syncthreads();                                 // (5)

        // ---- conv2 MFMA, full K=576 on waves 0,1; B read from H1T
        if (w < 2) {
            f4v c2 = (f4v){0.f, 0.f, 0.f, 0.f};
            const short* hbase = H1T + (20 * (lm >> 2) + 2 * (lm & 3)) * 72 + lq * 8;
            #pragma unroll
            for (int ks = 0; ks < 18; ++ks) {
                const int tap = ks >> 1;
                const int ky = tap / 3, kx = tap - 3 * ky;   // compile-time
                s8v a = (ks == 0) ? wa0 : (ks == 1) ? wa1
                      : *(const s8v*)(wrow + ks * 32);
                s8v bb = *(const s8v*)(hbase + (ky * 10 + kx) * 72 + (ks & 1) * 32);
                c2 = MFMA(a, bb, c2);
            }
            #pragma unroll
            for (int r = 0; r < 4; ++r) {
                const int oc = (w & 1) * 16 + lq * 4 + r;
                float v = c2[r];
                h2pre[(size_t)b * 512 + oc * 16 + lm] = v;
                float s1 = v, s2 = v * v;
                #pragma unroll
                for (int m = 1; m < 16; m <<= 1) {
                    s1 += __shfl_xor(s1, m, 16);
                    s2 += __shfl_xor(s2, m, 16);
                }
                if (lm == 0) { CS[oc] += s1; CS2[oc] += s2; }
            }
        }
        __syncthreads();   // (6) H1T reads done before next img / final read
    }

    if (t < 64) {                         // ONE atomic set/block: 16 RMW/addr
        const float v = (t < 32) ? CS[t] : CS2[t - 32];
        atomicAdd(&bn2r[(blockIdx.x & 63) * 64 + t], v);
    }
}

// ---------------------------------------------------------------------------
// stage2: 4 b per block (512 blocks). reduce bn2 replicas, BN2+lrelu, conv3,
// BN3 partials -> replicated bn3r[blockIdx&31][32]
// ---------------------------------------------------------------------------
__global__ __launch_bounds__(256) void stage2(
    const float* __restrict__ h2pre,
    const float* __restrict__ gamma2, const float* __restrict__ beta2,
    const float* __restrict__ w3,
    const float* __restrict__ bn2r,
    float* __restrict__ h3pre,
    float* __restrict__ bn3r, int B)
{
    const int b0 = blockIdx.x * 4, t = threadIdx.x;
    __shared__ float s_sums[64];
    __shared__ float s_scale[32], s_shift[32];
    __shared__ float s_pad[4 * 32 * 36];
    __shared__ float s_c3[16], s_c32[16];

    if (t < 64) {                          // reduce 64 replicas
        float s = 0.f;
        #pragma unroll
        for (int r = 0; r < 64; ++r) s += bn2r[r * 64 + t];
        s_sums[t] = s;
    }
    if (t < 16) { s_c3[t] = 0.f; s_c32[t] = 0.f; }
    for (int i = t; i < 4 * 32 * 36; i += 256) s_pad[i] = 0.f;
    __syncthreads();

    if (t < 32) {
        const float n = (float)B * 16.f;
        const float mean = s_sums[t] / n;
        const float var  = s_sums[32 + t] / n - mean * mean;
        const float sc   = gamma2[t] * rsqrtf(var + BN_EPS);
        s_scale[t] = sc;
        s_shift[t] = beta2[t] - mean * sc;
    }
    __syncthreads();

    for (int i = t; i < 2048; i += 256) {
        const int lb = i >> 9, r = i & 511;
        const int c = r >> 4, p = r & 15, y = p >> 2, x = p & 3;
        const float v = h2pre[(size_t)b0 * 512 + i] * s_scale[c] + s_shift[c];
        const float a = (v >= 0.f) ? v : SLOPE * v;
        s_pad[lb * 1152 + c * 36 + (y + 1) * 6 + (x + 1)] = a;
    }
    __syncthreads();

    {
        const int lb = t >> 6, r = t & 63;
        const int oc = r >> 2, p = r & 3, y = p >> 1, x = p & 1;
        float acc = 0.f;
        const float* wp = w3 + oc * 288;
        const float* hp = &s_pad[lb * 1152];
        for (int c = 0; c < 32; ++c) {
            const float* hc = hp + c * 36;
            #pragma unroll
            for (int ky = 0; ky < 3; ++ky)
                #pragma unroll
                for (int kx = 0; kx < 3; ++kx)
                    acc += wp[c * 9 + ky * 3 + kx] * hc[(2 * y + ky) * 6 + (2 * x + kx)];
        }
        h3pre[(size_t)b0 * 64 + t] = acc;
        atomicAdd(&s_c3[oc],  acc);
        atomicAdd(&s_c32[oc], acc * acc);
    }
    __syncthreads();
    if (t < 32) {                          // replicated: 16 RMWs/address
        const float v = (t < 16) ? s_c3[t] : s_c32[t - 16];
        atomicAdd(&bn3r[(blockIdx.x & 31) * 32 + t], v);
    }
}

// ---------------------------------------------------------------------------
// stage3: reduce bn3 replicas (32), BN3 + lrelu -> out
// ---------------------------------------------------------------------------
__global__ __launch_bounds__(256) void stage3(
    const float* __restrict__ h3pre,
    const float* __restrict__ gamma3, const float* __restrict__ beta3,
    const float* __restrict__ bn3r,
    float* __restrict__ out, int total, int B)
{
    __shared__ float s_tmp[32];
    __shared__ float s_scale[16], s_shift[16];
    if (threadIdx.x < 32) {                // reduce 32 replicas
        float s = 0.f;
        #pragma unroll
        for (int r = 0; r < 32; ++r) s += bn3r[r * 32 + threadIdx.x];
        s_tmp[threadIdx.x] = s;
    }
    __syncthreads();
    if (threadIdx.x < 16) {
        const int c = threadIdx.x;
        const float n = (float)B * 4.f;
        const float mean = s_tmp[c] / n;
        const float var  = s_tmp[16 + c] / n - mean * mean;
        const float sc   = gamma3[c] * rsqrtf(var + BN_EPS);
        s_scale[c] = sc;
        s_shift[c] = beta3[c] - mean * sc;
    }
    __syncthreads();
    const int idx = blockIdx.x * 256 + threadIdx.x;
    if (idx < total) {
        const int c = (idx & 63) >> 2;
        const float v = h3pre[idx] * s_scale[c] + s_shift[c];
        out[idx] = (v >= 0.f) ? v : SLOPE * v;
    }
}

extern "C" void kernel_launch(void* const* d_in, const int* in_sizes, int n_in,
                              void* d_out, int out_size, void* d_ws, size_t ws_size,
                              hipStream_t stream)
{
    const float* labels = (const float*)d_in[0];
    const float* theta  = (const float*)d_in[1];
    const float* w1     = (const float*)d_in[2];
    const float* w2     = (const float*)d_in[3];
    const float* gamma2 = (const float*)d_in[4];
    const float* beta2  = (const float*)d_in[5];
    const float* w3     = (const float*)d_in[6];
    const float* gamma3 = (const float*)d_in[7];
    const float* beta3  = (const float*)d_in[8];
    const int*   maxobj = (const int*)d_in[9];

    const int B = in_sizes[0] / (O_MAX * C_DIM);   // 2048

    unsigned char* ws = (unsigned char*)d_ws;
    float* h2pre = (float*)ws;                                  // B*512 f32
    float* h3pre = h2pre + (size_t)B * 512;                     // B*64
    float* sums  = h3pre + (size_t)B * 64;                      // 5120
    short* w1n   = (short*)(sums + N_SUMS);                     // 73728 sh
    short* w2b   = w1n + N_W1N;                                 // 18432 sh
    float* bn2r  = sums;                                        // [64][64]
    float* bn3r  = sums + 4096;                                 // [32][32]

    const int prep_total = N_W1N + N_W2B + N_SUMS;
    prep<<<(prep_total + 255) / 256, 256, 0, stream>>>(w1, w2, w1n, w2b, sums);
    stage1<<<B / 2, 256, 0, stream>>>(labels, theta, w1n, w2b, maxobj,
                                      h2pre, bn2r);
    stage2<<<B / 4, 256, 0, stream>>>(h2pre, gamma2, beta2, w3, bn2r,
                                      h3pre, bn3r, B);
    const int total = B * 64;
    stage3<<<(total + 255) / 256, 256, 0, stream>>>(h3pre, gamma3, beta3,
                                                    bn3r, (float*)d_out,
                                                    total, B);
}

// Round 15
// 174.720 us; speedup vs baseline: 1.1325x; 1.1325x over previous
//
#include <hip/hip_runtime.h>

#define C_DIM   128
#define O_MAX   10
#define BN_EPS  1e-5f
#define SLOPE   0.2f

typedef short s8v  __attribute__((ext_vector_type(8)));   // 8 bf16 (4 VGPRs)
typedef float f4v  __attribute__((ext_vector_type(4)));   // MFMA accumulator
#define MFMA(a,b,c) __builtin_amdgcn_mfma_f32_16x16x32_bf16(a,b,c,0,0,0)

__device__ inline unsigned short f2bf(float f) {          // RNE fp32->bf16
    unsigned u = __float_as_uint(f);
    unsigned r = u + 0x7FFFu + ((u >> 16) & 1u);
    return (unsigned short)(r >> 16);
}

// ---------------------------------------------------------------------------
// prep: w1n[n=(kk,oc)][c=128] bf16 ; w2b[oc][k2=tap*64+c] bf16 (tight 576) ;
// zero replicated BN buffers: bn2r[64][64] + bn3r[32][32] = 5120 f.
// ---------------------------------------------------------------------------
#define N_W1N  73728
#define N_W2B  18432       /* 32*576 */
#define N_SUMS 5120        /* 4096 bn2r + 1024 bn3r */
__global__ __launch_bounds__(256) void prep(
    const float* __restrict__ w1, const float* __restrict__ w2,
    short* __restrict__ w1n, short* __restrict__ w2b,
    float* __restrict__ sums)
{
    int i = blockIdx.x * 256 + threadIdx.x;
    if (i < N_W1N) {                       // w1n[n][c] = w1[oc][c][kk], n=kk*64+oc
        int n = i >> 7, c = i & 127;
        int kk = n >> 6, oc = n & 63;
        w1n[i] = f2bf(w1[oc * 1152 + c * 9 + kk]);
        return;
    }
    i -= N_W1N;
    if (i < N_W2B) {                       // w2b[oc][k2], k2 = tap*64+c
        int oc = i / 576, k2 = i % 576;
        int tap = k2 >> 6, c = k2 & 63;
        w2b[i] = f2bf(w2[oc * 576 + c * 9 + tap]);
        return;
    }
    i -= N_W2B;
    if (i < N_SUMS) sums[i] = 0.f;
}

// ---------------------------------------------------------------------------
// stage1 (B/2 = 1024 blocks, 256 thr; nimg=2 images per block, RUNTIME loop
// bound so the compiler CANNOT unroll -> register allocation matches the
// single-image body (~56-70 VGPR, no spills).  4th and clean version of the
// WG-launch-rate discriminator: r12 data = 40.5 WG/us @ VGPR 56; r13 (full
// unroll, VGPR 140) = 11.4 WG/us; r14 (forced 40 + spills) = spill-bound.
// If rate recovers at clean ~60 VGPR, halved WG count -> stage1 ~28-40 us.
// LDS identical to r12: 25072 B.
// ---------------------------------------------------------------------------
__global__ __launch_bounds__(256) void stage1(
    const float* __restrict__ labels,   // (B,10,128) fp32
    const float* __restrict__ theta,
    const short* __restrict__ w1n,      // (576,128) bf16, n=kk*64+oc
    const short* __restrict__ w2b,      // (32,576) bf16
    const int*   __restrict__ maxobj_p,
    float* __restrict__ h2pre,          // (B,32,4,4)
    float* __restrict__ bn2r,           // (64 reps, 64) s1[0:32] s2[32:64]
    int nimg)                           // runtime: blocks loop nimg images
{
    __shared__ __align__(16) unsigned char smem[25072];
    short* CPT  = (short*)(smem);             // [p=64][k stride 96]
    short* AT2  = (short*)(smem + 12288);     // [oc=64][k stride 96]
    short* LBF  = (short*)(smem + 12288);     // [m=16][c stride 136] overlay
    short* H1T  = (short*)(smem);             // [pix=100][oc stride 72]
    float* TH   = (float*)(smem + 24576);
    float* CS   = (float*)(smem + 24816);
    float* CS2  = (float*)(smem + 24944);

    const int t = threadIdx.x;
    const int w = t >> 6, l = t & 63, lm = l & 15, lq = l >> 4;
    const int nobj = min(maxobj_p[0], O_MAX);
    const short* brow_base = w1n + (size_t)(w * 144 + lm) * 128 + lq * 8;
    const short* wrow = w2b + (size_t)((w & 1) * 16 + lm) * 576 + lq * 8;

    if (t < 32) CS[t] = 0.f;
    else if (t < 64) CS2[t - 32] = 0.f;

    for (int img = 0; img < nimg; ++img) {     // runtime bound: NOT unrollable
        const int b = blockIdx.x * nimg + img;

        // ---- phase 0: LBF rows 0-9, rows 10-15 zero; TH; CPT k-tail zero
        for (int i = t; i < 320; i += 256) {             // 10 rows x 32 float4
            float4 v = *(const float4*)&labels[(size_t)b * 1280 + i * 4];
            const int row = i >> 5, c4 = i & 31;
            unsigned lo = f2bf(v.x) | ((unsigned)f2bf(v.y) << 16);
            unsigned hi = f2bf(v.z) | ((unsigned)f2bf(v.w) << 16);
            *(uint2*)&LBF[row * 136 + c4 * 4] = make_uint2(lo, hi);
        }
        for (int i = t; i < 384; i += 256) {             // rows 10-15 x 64 u32
            const int row = 10 + (i >> 6), cu = i & 63;
            *(unsigned*)&LBF[row * 136 + cu * 2] = 0u;
        }
        for (int i = t; i < 384; i += 256) {             // CPT k in [90,96)
            const int p = i / 6, j = i - 6 * p;
            CPT[p * 96 + 90 + j] = 0;
        }
        if (t < 60) TH[t] = theta[b * 60 + t];
        __syncthreads();                                 // (1)

        // ---- afr from LBF, then barrier -> LBF region reusable as AT2
        s8v afr[4];
        #pragma unroll
        for (int ks = 0; ks < 4; ++ks)
            afr[ks] = *(const s8v*)&LBF[lm * 136 + lq * 8 + ks * 32];
        __syncthreads();                                 // (2)

        s8v bcur[4], bnxt[4];
        #pragma unroll
        for (int ks = 0; ks < 4; ++ks)
            bcur[ks] = *(const s8v*)(brow_base + ks * 32);
        #pragma unroll
        for (int ks = 0; ks < 4; ++ks)
            bnxt[ks] = *(const s8v*)(brow_base + 16 * 128 + ks * 32);

        // AT2 k-tail zero (read in conv1, after barrier 3)
        for (int i = t; i < 384; i += 256) {
            const int p = i / 6, j = i - 6 * p;
            AT2[p * 96 + 90 + j] = 0;
        }

        // ---- phase 1a: CPT[p][o*9+kk].  gx,gy affine in (kx,ky).
        for (int i = t; i < 640; i += 256) {             // 64 p x 10 o
            const int p = i & 63, o = i >> 6;
            short* cp = &CPT[p * 96 + o * 9];
            if (o >= nobj) {
                #pragma unroll
                for (int kk = 0; kk < 9; ++kk) cp[kk] = 0;
                continue;
            }
            const int y = p >> 3, x = p & 7;
            const float* tt = &TH[o * 6];
            const float t0 = tt[0], t1 = tt[1], t2 = tt[2];
            const float t3 = tt[3], t4 = tt[4], t5 = tt[5];
            const float X0 = 0.25f * (float)x - 1.0625f;
            const float Y0 = 0.25f * (float)y - 1.0625f;
            const float GX0 = t0 * X0 + t1 * Y0 + t2;
            const float GY0 = t3 * X0 + t4 * Y0 + t5;
            const float dxg = 0.125f * t0, dyg = 0.125f * t1;
            const float dxh = 0.125f * t3, dyh = 0.125f * t4;
            #pragma unroll
            for (int ky = 0; ky < 3; ++ky) {
                const bool oky = (ky == 0) ? (y > 0) : true;  // py<=15 for ky>=1
                const float RX = GX0 + (float)ky * dyg;
                const float RY = GY0 + (float)ky * dyh;
                #pragma unroll
                for (int kx = 0; kx < 3; ++kx) {
                    const bool okx = (kx == 0) ? (x > 0) : true;
                    float val = 0.f;
                    if (oky && okx) {
                        const float gx = RX + (float)kx * dxg;
                        const float gy = RY + (float)kx * dxh;
                        float ix = gx * 8.f + 7.5f;
                        float x0 = floorf(ix), fx = ix - x0;
                        float cx = (1.f - fx) * ((x0 >= 0.f  && x0 <= 15.f) ? 1.f : 0.f)
                                 +        fx  * ((x0 >= -1.f && x0 <= 14.f) ? 1.f : 0.f);
                        float iy = gy * 8.f + 7.5f;
                        float y0 = floorf(iy), fy = iy - y0;
                        float cy = (1.f - fy) * ((y0 >= 0.f  && y0 <= 15.f) ? 1.f : 0.f)
                                 +        fy  * ((y0 >= -1.f && y0 <= 14.f) ? 1.f : 0.f);
                        val = cx * cy;
                    }
                    cp[ky * 3 + kx] = (short)f2bf(val);
                }
            }
        }

        // ---- phase 1b: pipelined A-GEMM. wave w owns n in [w*144,w*144+144)
        #pragma unroll
        for (int nt = 0; nt < 9; ++nt) {
            f4v acc = (f4v){0.f, 0.f, 0.f, 0.f};
            #pragma unroll
            for (int ks = 0; ks < 4; ++ks)
                acc = MFMA(afr[ks], bcur[ks], acc);
            #pragma unroll
            for (int ks = 0; ks < 4; ++ks) bcur[ks] = bnxt[ks];
            if (nt < 7) {
                #pragma unroll
                for (int ks = 0; ks < 4; ++ks)
                    bnxt[ks] = *(const s8v*)(brow_base + (size_t)(nt + 2) * 16 * 128 + ks * 32);
            }
            const int n = w * 144 + nt * 16 + lm;
            const int kk = n >> 6, oc = n & 63;
            #pragma unroll
            for (int r = 0; r < 4; ++r) {
                const int m = lq * 4 + r;
                if (m < 10)
                    AT2[oc * 96 + m * 9 + kk] = (short)f2bf(acc[r]);
            }
        }
        __syncthreads();                                 // (3)

        // ---- conv1 MFMA.  wave w -> oc tile [16w,16w+16); K=96
        f4v c1[4];
        #pragma unroll
        for (int nt = 0; nt < 4; ++nt) c1[nt] = (f4v){0.f, 0.f, 0.f, 0.f};
        {
            const short* at = AT2 + (16 * w + lm) * 96 + lq * 8;
            const short* cp = CPT + lm * 96 + lq * 8;
            #pragma unroll
            for (int ks = 0; ks < 3; ++ks) {
                s8v a = *(const s8v*)(at + ks * 32);
                #pragma unroll
                for (int nt = 0; nt < 4; ++nt) {
                    s8v bb = *(const s8v*)(cp + nt * 1536 + ks * 32);
                    c1[nt] = MFMA(a, bb, c1[nt]);
                }
            }
        }
        __syncthreads();                                 // (4)

        // conv1 epilogue: zero H1T border rows, write lrelu(bf16) interior
        for (int i = t; i < 1152; i += 256) {           // 36 border pix x 32 u32
            const int j = i >> 5, col = i & 31;
            int r;
            if (j < 10) r = j;
            else if (j < 20) r = 90 + (j - 10);
            else { int jj = j - 20; r = 10 + (jj >> 1) * 10 + ((jj & 1) ? 9 : 0); }
            ((unsigned*)H1T)[r * 36 + col] = 0u;
        }
        #pragma unroll
        for (int nt = 0; nt < 4; ++nt) {
            const int p = nt * 16 + lm, y = p >> 3, x = p & 7;
            const int pix = (y + 1) * 10 + (x + 1);
            #pragma unroll
            for (int r = 0; r < 4; ++r) {
                const int oc = 16 * w + lq * 4 + r;
                float v = c1[nt][r];
                v = (v >= 0.f) ? v : SLOPE * v;
                H1T[pix * 72 + oc] = (short)f2bf(v);
            }
        }

        // prefetch conv2 A-operand before barrier
        s8v wa0, wa1;
        if (w < 2) {
            wa0 = *(const s8v*)(wrow);
            wa1 = *(const s8v*)(wrow + 32);
        }
        __syncthreads();                                 // (5)

        // ---- conv2 MFMA, full K=576 on waves 0,1; B read from H1T
        if (w < 2) {
            f4v c2 = (f4v){0.f, 0.f, 0.f, 0.f};
            const short* hbase = H1T + (20 * (lm >> 2) + 2 * (lm & 3)) * 72 + lq * 8;
            #pragma unroll
            for (int ks = 0; ks < 18; ++ks) {
                const int tap = ks >> 1;
                const int ky = tap / 3, kx = tap - 3 * ky;   // compile-time
                s8v a = (ks == 0) ? wa0 : (ks == 1) ? wa1
                      : *(const s8v*)(wrow + ks * 32);
                s8v bb = *(const s8v*)(hbase + (ky * 10 + kx) * 72 + (ks & 1) * 32);
                c2 = MFMA(a, bb, c2);
            }
            #pragma unroll
            for (int r = 0; r < 4; ++r) {
                const int oc = (w & 1) * 16 + lq * 4 + r;
                float v = c2[r];
                h2pre[(size_t)b * 512 + oc * 16 + lm] = v;
                float s1 = v, s2 = v * v;
                #pragma unroll
                for (int m = 1; m < 16; m <<= 1) {
                    s1 += __shfl_xor(s1, m, 16);
                    s2 += __shfl_xor(s2, m, 16);
                }
                if (lm == 0) { CS[oc] += s1; CS2[oc] += s2; }
            }
        }
        __syncthreads();   // (6) H1T reads done before next img / final read
    }

    if (t < 64) {                         // ONE atomic set/block: 16 RMW/addr
        const float v = (t < 32) ? CS[t] : CS2[t - 32];
        atomicAdd(&bn2r[(blockIdx.x & 63) * 64 + t], v);
    }
}

// ---------------------------------------------------------------------------
// stage2: 4 b per block (512 blocks). reduce bn2 replicas, BN2+lrelu, conv3,
// BN3 partials -> replicated bn3r[blockIdx&31][32]
// ---------------------------------------------------------------------------
__global__ __launch_bounds__(256) void stage2(
    const float* __restrict__ h2pre,
    const float* __restrict__ gamma2, const float* __restrict__ beta2,
    const float* __restrict__ w3,
    const float* __restrict__ bn2r,
    float* __restrict__ h3pre,
    float* __restrict__ bn3r, int B)
{
    const int b0 = blockIdx.x * 4, t = threadIdx.x;
    __shared__ float s_sums[64];
    __shared__ float s_scale[32], s_shift[32];
    __shared__ float s_pad[4 * 32 * 36];
    __shared__ float s_c3[16], s_c32[16];

    if (t < 64) {                          // reduce 64 replicas
        float s = 0.f;
        #pragma unroll
        for (int r = 0; r < 64; ++r) s += bn2r[r * 64 + t];
        s_sums[t] = s;
    }
    if (t < 16) { s_c3[t] = 0.f; s_c32[t] = 0.f; }
    for (int i = t; i < 4 * 32 * 36; i += 256) s_pad[i] = 0.f;
    __syncthreads();

    if (t < 32) {
        const float n = (float)B * 16.f;
        const float mean = s_sums[t] / n;
        const float var  = s_sums[32 + t] / n - mean * mean;
        const float sc   = gamma2[t] * rsqrtf(var + BN_EPS);
        s_scale[t] = sc;
        s_shift[t] = beta2[t] - mean * sc;
    }
    __syncthreads();

    for (int i = t; i < 2048; i += 256) {
        const int lb = i >> 9, r = i & 511;
        const int c = r >> 4, p = r & 15, y = p >> 2, x = p & 3;
        const float v = h2pre[(size_t)b0 * 512 + i] * s_scale[c] + s_shift[c];
        const float a = (v >= 0.f) ? v : SLOPE * v;
        s_pad[lb * 1152 + c * 36 + (y + 1) * 6 + (x + 1)] = a;
    }
    __syncthreads();

    {
        const int lb = t >> 6, r = t & 63;
        const int oc = r >> 2, p = r & 3, y = p >> 1, x = p & 1;
        float acc = 0.f;
        const float* wp = w3 + oc * 288;
        const float* hp = &s_pad[lb * 1152];
        for (int c = 0; c < 32; ++c) {
            const float* hc = hp + c * 36;
            #pragma unroll
            for (int ky = 0; ky < 3; ++ky)
                #pragma unroll
                for (int kx = 0; kx < 3; ++kx)
                    acc += wp[c * 9 + ky * 3 + kx] * hc[(2 * y + ky) * 6 + (2 * x + kx)];
        }
        h3pre[(size_t)b0 * 64 + t] = acc;
        atomicAdd(&s_c3[oc],  acc);
        atomicAdd(&s_c32[oc], acc * acc);
    }
    __syncthreads();
    if (t < 32) {                          // replicated: 16 RMWs/address
        const float v = (t < 16) ? s_c3[t] : s_c32[t - 16];
        atomicAdd(&bn3r[(blockIdx.x & 31) * 32 + t], v);
    }
}

// ---------------------------------------------------------------------------
// stage3: reduce bn3 replicas (32), BN3 + lrelu -> out
// ---------------------------------------------------------------------------
__global__ __launch_bounds__(256) void stage3(
    const float* __restrict__ h3pre,
    const float* __restrict__ gamma3, const float* __restrict__ beta3,
    const float* __restrict__ bn3r,
    float* __restrict__ out, int total, int B)
{
    __shared__ float s_tmp[32];
    __shared__ float s_scale[16], s_shift[16];
    if (threadIdx.x < 32) {                // reduce 32 replicas
        float s = 0.f;
        #pragma unroll
        for (int r = 0; r < 32; ++r) s += bn3r[r * 32 + threadIdx.x];
        s_tmp[threadIdx.x] = s;
    }
    __syncthreads();
    if (threadIdx.x < 16) {
        const int c = threadIdx.x;
        const float n = (float)B * 4.f;
        const float mean = s_tmp[c] / n;
        const float var  = s_tmp[16 + c] / n - mean * mean;
        const float sc   = gamma3[c] * rsqrtf(var + BN_EPS);
        s_scale[c] = sc;
        s_shift[c] = beta3[c] - mean * sc;
    }
    __syncthreads();
    const int idx = blockIdx.x * 256 + threadIdx.x;
    if (idx < total) {
        const int c = (idx & 63) >> 2;
        const float v = h3pre[idx] * s_scale[c] + s_shift[c];
        out[idx] = (v >= 0.f) ? v : SLOPE * v;
    }
}

extern "C" void kernel_launch(void* const* d_in, const int* in_sizes, int n_in,
                              void* d_out, int out_size, void* d_ws, size_t ws_size,
                              hipStream_t stream)
{
    const float* labels = (const float*)d_in[0];
    const float* theta  = (const float*)d_in[1];
    const float* w1     = (const float*)d_in[2];
    const float* w2     = (const float*)d_in[3];
    const float* gamma2 = (const float*)d_in[4];
    const float* beta2  = (const float*)d_in[5];
    const float* w3     = (const float*)d_in[6];
    const float* gamma3 = (const float*)d_in[7];
    const float* beta3  = (const float*)d_in[8];
    const int*   maxobj = (const int*)d_in[9];

    const int B = in_sizes[0] / (O_MAX * C_DIM);   // 2048

    unsigned char* ws = (unsigned char*)d_ws;
    float* h2pre = (float*)ws;                                  // B*512 f32
    float* h3pre = h2pre + (size_t)B * 512;                     // B*64
    float* sums  = h3pre + (size_t)B * 64;                      // 5120
    short* w1n   = (short*)(sums + N_SUMS);                     // 73728 sh
    short* w2b   = w1n + N_W1N;                                 // 18432 sh
    float* bn2r  = sums;                                        // [64][64]
    float* bn3r  = sums + 4096;                                 // [32][32]

    const int prep_total = N_W1N + N_W2B + N_SUMS;
    prep<<<(prep_total + 255) / 256, 256, 0, stream>>>(w1, w2, w1n, w2b, sums);
    stage1<<<B / 2, 256, 0, stream>>>(labels, theta, w1n, w2b, maxobj,
                                      h2pre, bn2r, 2);
    stage2<<<B / 4, 256, 0, stream>>>(h2pre, gamma2, beta2, w3, bn2r,
                                      h3pre, bn3r, B);
    const int total = B * 64;
    stage3<<<(total + 255) / 256, 256, 0, stream>>>(h3pre, gamma3, beta3,
                                                    bn3r, (float*)d_out,
                                                    total, B);
}

// Round 16
// 135.142 us; speedup vs baseline: 1.4641x; 1.2929x over previous
//
#include <hip/hip_runtime.h>

#define C_DIM   128
#define O_MAX   10
#define BN_EPS  1e-5f
#define SLOPE   0.2f

typedef short s8v  __attribute__((ext_vector_type(8)));   // 8 bf16 (4 VGPRs)
typedef float f4v  __attribute__((ext_vector_type(4)));   // MFMA accumulator
#define MFMA(a,b,c) __builtin_amdgcn_mfma_f32_16x16x32_bf16(a,b,c,0,0,0)

__device__ inline unsigned short f2bf(float f) {          // RNE fp32->bf16
    unsigned u = __float_as_uint(f);
    unsigned r = u + 0x7FFFu + ((u >> 16) & 1u);
    return (unsigned short)(r >> 16);
}

// ---------------------------------------------------------------------------
// prep: w1n[n=(kk,oc)][c=128] bf16 ; w2b[oc][k2=tap*64+c] bf16 (tight 576) ;
// zero replicated BN buffers: bn2r[64][64] + bn3r[32][32] = 5120 f.
// ---------------------------------------------------------------------------
#define N_W1N  73728
#define N_W2B  18432       /* 32*576 */
#define N_SUMS 5120        /* 4096 bn2r + 1024 bn3r */
__global__ __launch_bounds__(256) void prep(
    const float* __restrict__ w1, const float* __restrict__ w2,
    short* __restrict__ w1n, short* __restrict__ w2b,
    float* __restrict__ sums)
{
    int i = blockIdx.x * 256 + threadIdx.x;
    if (i < N_W1N) {                       // w1n[n][c] = w1[oc][c][kk], n=kk*64+oc
        int n = i >> 7, c = i & 127;
        int kk = n >> 6, oc = n & 63;
        w1n[i] = f2bf(w1[oc * 1152 + c * 9 + kk]);
        return;
    }
    i -= N_W1N;
    if (i < N_W2B) {                       // w2b[oc][k2], k2 = tap*64+c
        int oc = i / 576, k2 = i % 576;
        int tap = k2 >> 6, c = k2 & 63;
        w2b[i] = f2bf(w2[oc * 576 + c * 9 + tap]);
        return;
    }
    i -= N_W2B;
    if (i < N_SUMS) sums[i] = 0.f;
}

// ---------------------------------------------------------------------------
// stage1 (per-b block, 256 thr; measured 50.6-52 us, session-best config):
//   phase0: LBF bf16 (stride 136, overlaid on AT2), TH, CPT k-tail zero
//   phase1: afr loads -> barrier (LBF dead) -> w1n prefetch -> CPT direct
//     from theta (affine in kx,ky) -> pipelined A-GEMM -> AT2
//   conv1 MFMA -> lrelu -> H1T (stride 72) ; conv2 MFMA direct from H1T ;
//   BN2 partials -> replicated bn2r[b&63][64] (32 RMW/address).
// LDS: CPT [64][96] 0..12288 | AT2 [64][96] 12288..24576 | LBF overlay
//   12288..16640 | TH 24576..24816 | CS 24816..24944 | CS2 24944..25072 ;
//   overlay H1T [100][72] 0..14400 after conv1.  Total 25072 B.
// Session notes (measured): VGPR 56, occ ~35%, launch-rate/latency-bound;
// bank conflicts & occupancy levers null; fat blocks (2 img/blk) always
// compile to VGPR 140 -> ~90 us; cg/soft grid-sync fusion costs +35-100 us.
// ---------------------------------------------------------------------------
__global__ __launch_bounds__(256) void stage1(
    const float* __restrict__ labels,   // (B,10,128) fp32
    const float* __restrict__ theta,
    const short* __restrict__ w1n,      // (576,128) bf16, n=kk*64+oc
    const short* __restrict__ w2b,      // (32,576) bf16
    const int*   __restrict__ maxobj_p,
    float* __restrict__ h2pre,          // (B,32,4,4)
    float* __restrict__ bn2r)           // (64 reps, 64) s1[0:32] s2[32:64]
{
    __shared__ __align__(16) unsigned char smem[25072];
    short* CPT  = (short*)(smem);             // [p=64][k stride 96]
    short* AT2  = (short*)(smem + 12288);     // [oc=64][k stride 96]
    short* LBF  = (short*)(smem + 12288);     // [m=16][c stride 136] overlay
    short* H1T  = (short*)(smem);             // [pix=100][oc stride 72]
    float* TH   = (float*)(smem + 24576);
    float* CS   = (float*)(smem + 24816);
    float* CS2  = (float*)(smem + 24944);

    const int b = blockIdx.x, t = threadIdx.x;
    const int w = t >> 6, l = t & 63, lm = l & 15, lq = l >> 4;
    const int nobj = min(maxobj_p[0], O_MAX);

    // ---- phase 0: LBF rows 0-9 from labels, rows 10-15 zero; TH; CPT k-tail
    for (int i = t; i < 320; i += 256) {             // 10 rows x 32 float4
        float4 v = *(const float4*)&labels[(size_t)b * 1280 + i * 4];
        const int row = i >> 5, c4 = i & 31;
        unsigned lo = f2bf(v.x) | ((unsigned)f2bf(v.y) << 16);
        unsigned hi = f2bf(v.z) | ((unsigned)f2bf(v.w) << 16);
        *(uint2*)&LBF[row * 136 + c4 * 4] = make_uint2(lo, hi);
    }
    for (int i = t; i < 384; i += 256) {             // rows 10-15 x 64 u32
        const int row = 10 + (i >> 6), cu = i & 63;
        *(unsigned*)&LBF[row * 136 + cu * 2] = 0u;
    }
    for (int i = t; i < 384; i += 256) {             // CPT 64 rows x k in [90,96)
        const int p = i / 6, j = i - 6 * p;
        CPT[p * 96 + 90 + j] = 0;
    }
    if (t < 60) TH[t] = theta[b * 60 + t];
    __syncthreads();

    // ---- phase 1: afr from LBF, then barrier -> LBF region reusable as AT2
    s8v afr[4];
    #pragma unroll
    for (int ks = 0; ks < 4; ++ks)
        afr[ks] = *(const s8v*)&LBF[lm * 136 + lq * 8 + ks * 32];
    __syncthreads();                                 // all LBF reads complete

    const short* brow_base = w1n + (size_t)(w * 144 + lm) * 128 + lq * 8;
    s8v bcur[4], bnxt[4];
    #pragma unroll
    for (int ks = 0; ks < 4; ++ks)
        bcur[ks] = *(const s8v*)(brow_base + ks * 32);
    #pragma unroll
    for (int ks = 0; ks < 4; ++ks)
        bnxt[ks] = *(const s8v*)(brow_base + 16 * 128 + ks * 32);

    // AT2 k-tail zero (reads of these happen in conv1, after next barrier)
    for (int i = t; i < 384; i += 256) {
        const int p = i / 6, j = i - 6 * p;
        AT2[p * 96 + 90 + j] = 0;
    }

    // ---- phase 1a: CPT[p][o*9+kk].  gx,gy affine in (kx,ky).
    for (int i = t; i < 640; i += 256) {             // 64 p x 10 o
        const int p = i & 63, o = i >> 6;
        short* cp = &CPT[p * 96 + o * 9];
        if (o >= nobj) {
            #pragma unroll
            for (int kk = 0; kk < 9; ++kk) cp[kk] = 0;
            continue;
        }
        const int y = p >> 3, x = p & 7;
        const float* tt = &TH[o * 6];
        const float t0 = tt[0], t1 = tt[1], t2 = tt[2];
        const float t3 = tt[3], t4 = tt[4], t5 = tt[5];
        const float X0 = 0.25f * (float)x - 1.0625f;   // kx=0 grid coord
        const float Y0 = 0.25f * (float)y - 1.0625f;
        const float GX0 = t0 * X0 + t1 * Y0 + t2;
        const float GY0 = t3 * X0 + t4 * Y0 + t5;
        const float dxg = 0.125f * t0, dyg = 0.125f * t1;
        const float dxh = 0.125f * t3, dyh = 0.125f * t4;
        #pragma unroll
        for (int ky = 0; ky < 3; ++ky) {
            const bool oky = (ky == 0) ? (y > 0) : true;   // py=2y+ky-1<=15 for ky>=1
            const float RX = GX0 + (float)ky * dyg;
            const float RY = GY0 + (float)ky * dyh;
            #pragma unroll
            for (int kx = 0; kx < 3; ++kx) {
                const bool okx = (kx == 0) ? (x > 0) : true;
                float val = 0.f;
                if (oky && okx) {
                    const float gx = RX + (float)kx * dxg;
                    const float gy = RY + (float)kx * dxh;
                    float ix = gx * 8.f + 7.5f;
                    float x0 = floorf(ix), fx = ix - x0;
                    float cx = (1.f - fx) * ((x0 >= 0.f  && x0 <= 15.f) ? 1.f : 0.f)
                             +        fx  * ((x0 >= -1.f && x0 <= 14.f) ? 1.f : 0.f);
                    float iy = gy * 8.f + 7.5f;
                    float y0 = floorf(iy), fy = iy - y0;
                    float cy = (1.f - fy) * ((y0 >= 0.f  && y0 <= 15.f) ? 1.f : 0.f)
                             +        fy  * ((y0 >= -1.f && y0 <= 14.f) ? 1.f : 0.f);
                    val = cx * cy;
                }
                cp[ky * 3 + kx] = (short)f2bf(val);
            }
        }
    }

    // ---- phase 1b: pipelined A-GEMM. wave w owns n in [w*144, w*144+144).
    #pragma unroll
    for (int nt = 0; nt < 9; ++nt) {
        f4v acc = (f4v){0.f, 0.f, 0.f, 0.f};
        #pragma unroll
        for (int ks = 0; ks < 4; ++ks)
            acc = MFMA(afr[ks], bcur[ks], acc);
        #pragma unroll
        for (int ks = 0; ks < 4; ++ks) bcur[ks] = bnxt[ks];
        if (nt < 7) {
            #pragma unroll
            for (int ks = 0; ks < 4; ++ks)
                bnxt[ks] = *(const s8v*)(brow_base + (size_t)(nt + 2) * 16 * 128 + ks * 32);
        }
        const int n = w * 144 + nt * 16 + lm;
        const int kk = n >> 6, oc = n & 63;
        #pragma unroll
        for (int r = 0; r < 4; ++r) {
            const int m = lq * 4 + r;
            if (m < 10)
                AT2[oc * 96 + m * 9 + kk] = (short)f2bf(acc[r]);
        }
    }
    __syncthreads();

    // ---- conv1 MFMA.  wave w -> oc tile [16w,16w+16); K=96
    f4v c1[4];
    #pragma unroll
    for (int nt = 0; nt < 4; ++nt) c1[nt] = (f4v){0.f, 0.f, 0.f, 0.f};
    {
        const short* at = AT2 + (16 * w + lm) * 96 + lq * 8;
        const short* cp = CPT + lm * 96 + lq * 8;
        #pragma unroll
        for (int ks = 0; ks < 3; ++ks) {
            s8v a = *(const s8v*)(at + ks * 32);
            #pragma unroll
            for (int nt = 0; nt < 4; ++nt) {
                s8v bb = *(const s8v*)(cp + nt * 1536 + ks * 32);
                c1[nt] = MFMA(a, bb, c1[nt]);
            }
        }
    }
    __syncthreads();   // CPT/AT2 reads done before H1T overlay writes

    // conv1 epilogue: zero H1T border pixel rows, write lrelu(bf16) interior
    for (int i = t; i < 1152; i += 256) {           // 36 border pix x 32 u32
        const int j = i >> 5, col = i & 31;
        int r;
        if (j < 10) r = j;
        else if (j < 20) r = 90 + (j - 10);
        else { int jj = j - 20; r = 10 + (jj >> 1) * 10 + ((jj & 1) ? 9 : 0); }
        ((unsigned*)H1T)[r * 36 + col] = 0u;
    }
    #pragma unroll
    for (int nt = 0; nt < 4; ++nt) {
        const int p = nt * 16 + lm, y = p >> 3, x = p & 7;
        const int pix = (y + 1) * 10 + (x + 1);
        #pragma unroll
        for (int r = 0; r < 4; ++r) {
            const int oc = 16 * w + lq * 4 + r;
            float v = c1[nt][r];
            v = (v >= 0.f) ? v : SLOPE * v;
            H1T[pix * 72 + oc] = (short)f2bf(v);
        }
    }

    // prefetch conv2 A-operand (global, independent of H1T) before barrier
    s8v wa0, wa1;
    const short* wrow = w2b + (size_t)((w & 1) * 16 + lm) * 576 + lq * 8;
    if (w < 2) {
        wa0 = *(const s8v*)(wrow);
        wa1 = *(const s8v*)(wrow + 32);
    }
    __syncthreads();

    // ---- conv2 MFMA, full K=576 on waves 0,1; B read from H1T directly
    if (w < 2) {
        f4v c2 = (f4v){0.f, 0.f, 0.f, 0.f};
        const short* hbase = H1T + (20 * (lm >> 2) + 2 * (lm & 3)) * 72 + lq * 8;
        #pragma unroll
        for (int ks = 0; ks < 18; ++ks) {
            const int tap = ks >> 1;
            const int ky = tap / 3, kx = tap - 3 * ky;       // compile-time
            s8v a = (ks == 0) ? wa0 : (ks == 1) ? wa1
                  : *(const s8v*)(wrow + ks * 32);
            s8v bb = *(const s8v*)(hbase + (ky * 10 + kx) * 72 + (ks & 1) * 32);
            c2 = MFMA(a, bb, c2);
        }
        #pragma unroll
        for (int r = 0; r < 4; ++r) {
            const int oc = w * 16 + lq * 4 + r;
            float v = c2[r];
            h2pre[(size_t)b * 512 + oc * 16 + lm] = v;
            float s1 = v, s2 = v * v;
            #pragma unroll
            for (int m = 1; m < 16; m <<= 1) {
                s1 += __shfl_xor(s1, m, 16);
                s2 += __shfl_xor(s2, m, 16);
            }
            if (lm == 0) { CS[oc] = s1; CS2[oc] = s2; }
        }
    }
    __syncthreads();
    if (t < 64) {                         // replicated: 32 RMWs/address
        const float v = (t < 32) ? CS[t] : CS2[t - 32];
        atomicAdd(&bn2r[(b & 63) * 64 + t], v);
    }
}

// ---------------------------------------------------------------------------
// stage2: 4 b per block (512 blocks). reduce bn2 replicas, BN2+lrelu, conv3,
// BN3 partials -> replicated bn3r[blockIdx&31][32]
// ---------------------------------------------------------------------------
__global__ __launch_bounds__(256) void stage2(
    const float* __restrict__ h2pre,
    const float* __restrict__ gamma2, const float* __restrict__ beta2,
    const float* __restrict__ w3,
    const float* __restrict__ bn2r,
    float* __restrict__ h3pre,
    float* __restrict__ bn3r, int B)
{
    const int b0 = blockIdx.x * 4, t = threadIdx.x;
    __shared__ float s_sums[64];
    __shared__ float s_scale[32], s_shift[32];
    __shared__ float s_pad[4 * 32 * 36];
    __shared__ float s_c3[16], s_c32[16];

    if (t < 64) {                          // reduce 64 replicas
        float s = 0.f;
        #pragma unroll
        for (int r = 0; r < 64; ++r) s += bn2r[r * 64 + t];
        s_sums[t] = s;
    }
    if (t < 16) { s_c3[t] = 0.f; s_c32[t] = 0.f; }
    for (int i = t; i < 4 * 32 * 36; i += 256) s_pad[i] = 0.f;
    __syncthreads();

    if (t < 32) {
        const float n = (float)B * 16.f;
        const float mean = s_sums[t] / n;
        const float var  = s_sums[32 + t] / n - mean * mean;
        const float sc   = gamma2[t] * rsqrtf(var + BN_EPS);
        s_scale[t] = sc;
        s_shift[t] = beta2[t] - mean * sc;
    }
    __syncthreads();

    for (int i = t; i < 2048; i += 256) {
        const int lb = i >> 9, r = i & 511;
        const int c = r >> 4, p = r & 15, y = p >> 2, x = p & 3;
        const float v = h2pre[(size_t)b0 * 512 + i] * s_scale[c] + s_shift[c];
        const float a = (v >= 0.f) ? v : SLOPE * v;
        s_pad[lb * 1152 + c * 36 + (y + 1) * 6 + (x + 1)] = a;
    }
    __syncthreads();

    {
        const int lb = t >> 6, r = t & 63;
        const int oc = r >> 2, p = r & 3, y = p >> 1, x = p & 1;
        float acc = 0.f;
        const float* wp = w3 + oc * 288;
        const float* hp = &s_pad[lb * 1152];
        for (int c = 0; c < 32; ++c) {
            const float* hc = hp + c * 36;
            #pragma unroll
            for (int ky = 0; ky < 3; ++ky)
                #pragma unroll
                for (int kx = 0; kx < 3; ++kx)
                    acc += wp[c * 9 + ky * 3 + kx] * hc[(2 * y + ky) * 6 + (2 * x + kx)];
        }
        h3pre[(size_t)b0 * 64 + t] = acc;
        atomicAdd(&s_c3[oc],  acc);
        atomicAdd(&s_c32[oc], acc * acc);
    }
    __syncthreads();
    if (t < 32) {                          // replicated: 16 RMWs/address
        const float v = (t < 16) ? s_c3[t] : s_c32[t - 16];
        atomicAdd(&bn3r[(blockIdx.x & 31) * 32 + t], v);
    }
}

// ---------------------------------------------------------------------------
// stage3: reduce bn3 replicas (32), BN3 + lrelu -> out
// ---------------------------------------------------------------------------
__global__ __launch_bounds__(256) void stage3(
    const float* __restrict__ h3pre,
    const float* __restrict__ gamma3, const float* __restrict__ beta3,
    const float* __restrict__ bn3r,
    float* __restrict__ out, int total, int B)
{
    __shared__ float s_tmp[32];
    __shared__ float s_scale[16], s_shift[16];
    if (threadIdx.x < 32) {                // reduce 32 replicas
        float s = 0.f;
        #pragma unroll
        for (int r = 0; r < 32; ++r) s += bn3r[r * 32 + threadIdx.x];
        s_tmp[threadIdx.x] = s;
    }
    __syncthreads();
    if (threadIdx.x < 16) {
        const int c = threadIdx.x;
        const float n = (float)B * 4.f;
        const float mean = s_tmp[c] / n;
        const float var  = s_tmp[16 + c] / n - mean * mean;
        const float sc   = gamma3[c] * rsqrtf(var + BN_EPS);
        s_scale[c] = sc;
        s_shift[c] = beta3[c] - mean * sc;
    }
    __syncthreads();
    const int idx = blockIdx.x * 256 + threadIdx.x;
    if (idx < total) {
        const int c = (idx & 63) >> 2;
        const float v = h3pre[idx] * s_scale[c] + s_shift[c];
        out[idx] = (v >= 0.f) ? v : SLOPE * v;
    }
}

extern "C" void kernel_launch(void* const* d_in, const int* in_sizes, int n_in,
                              void* d_out, int out_size, void* d_ws, size_t ws_size,
                              hipStream_t stream)
{
    const float* labels = (const float*)d_in[0];
    const float* theta  = (const float*)d_in[1];
    const float* w1     = (const float*)d_in[2];
    const float* w2     = (const float*)d_in[3];
    const float* gamma2 = (const float*)d_in[4];
    const float* beta2  = (const float*)d_in[5];
    const float* w3     = (const float*)d_in[6];
    const float* gamma3 = (const float*)d_in[7];
    const float* beta3  = (const float*)d_in[8];
    const int*   maxobj = (const int*)d_in[9];

    const int B = in_sizes[0] / (O_MAX * C_DIM);   // 2048

    unsigned char* ws = (unsigned char*)d_ws;
    float* h2pre = (float*)ws;                                  // B*512 f32
    float* h3pre = h2pre + (size_t)B * 512;                     // B*64
    float* sums  = h3pre + (size_t)B * 64;                      // 5120
    short* w1n   = (short*)(sums + N_SUMS);                     // 73728 sh
    short* w2b   = w1n + N_W1N;                                 // 18432 sh
    float* bn2r  = sums;                                        // [64][64]
    float* bn3r  = sums + 4096;                                 // [32][32]

    const int prep_total = N_W1N + N_W2B + N_SUMS;
    prep<<<(prep_total + 255) / 256, 256, 0, stream>>>(w1, w2, w1n, w2b, sums);
    stage1<<<B, 256, 0, stream>>>(labels, theta, w1n, w2b, maxobj,
                                  h2pre, bn2r);
    stage2<<<B / 4, 256, 0, stream>>>(h2pre, gamma2, beta2, w3, bn2r,
                                      h3pre, bn3r, B);
    const int total = B * 64;
    stage3<<<(total + 255) / 256, 256, 0, stream>>>(h3pre, gamma3, beta3,
                                                    bn3r, (float*)d_out,
                                                    total, B);
}